// Round 6
// baseline (279.902 us; speedup 1.0000x reference)
//
#include <hip/hip_runtime.h>
#include <hip/hip_bf16.h>

// Problem constants
#define B_DIM 4096
#define H_DIM 1024
#define K1    2048   // IN + H
#define N1    6144   // 5 gates * 1024 + a1 (1024)
#define N2    2048   // ssg (1024) + r1 (1024)
#define NT1   (K1 / 64)   // 32 K-tiles for the big GEMM

typedef __attribute__((ext_vector_type(8))) short bf16x8;
typedef __attribute__((ext_vector_type(4))) float f32x4;
typedef __attribute__((ext_vector_type(16))) float f32x16;

__device__ __forceinline__ unsigned short f2bf(float f) {
  unsigned int x = __float_as_uint(f);
  x += 0x7fffu + ((x >> 16) & 1u);   // RTNE
  return (unsigned short)(x >> 16);
}
__device__ __forceinline__ float bf2f(unsigned short u) {
  return __uint_as_float(((unsigned int)u) << 16);
}
__device__ __forceinline__ float fast_sigmoid(float x) {
  return __builtin_amdgcn_rcpf(1.0f + __expf(-x));
}
__device__ __forceinline__ float fast_tanh(float x) {
  return 1.0f - 2.0f * __builtin_amdgcn_rcpf(1.0f + __expf(2.0f * x));
}
__device__ __forceinline__ void gload_lds16(const void* g, void* l) {
  __builtin_amdgcn_global_load_lds(
      (const __attribute__((address_space(1))) void*)g,
      (__attribute__((address_space(3))) void*)l, 16, 0, 0);
}

// m201's st_16x32 swizzle: XOR byte-bit5 with bit9 within a 1024B subtile.
__device__ __forceinline__ int swz1k(int x) {
  return x ^ (((x >> 9) & 1) << 5);
}

// ---------------------------------------------------------------------------
// prep: build bf16 activations + weight panels in workspace (grid-stride vec4)
// ---------------------------------------------------------------------------
__global__ __launch_bounds__(256) void prep_kernel(
    const float* __restrict__ x, const float* __restrict__ h,
    const float* __restrict__ ssg_state,
    const float* __restrict__ Wx, const float* __restrict__ Ux,
    const float* __restrict__ a1_w,
    const float* __restrict__ ssg_w, const float* __restrict__ r1_w,
    const float* __restrict__ r2_w, const float* __restrict__ r3_w,
    unsigned short* __restrict__ combined,
    unsigned short* __restrict__ ssg_in,
    unsigned short* __restrict__ hprev_bf,
    unsigned short* __restrict__ W1,
    unsigned short* __restrict__ W2,
    unsigned short* __restrict__ W3,
    unsigned short* __restrict__ W4)
{
  const size_t NV0 = (size_t)B_DIM * K1 / 4;      // combined
  const size_t NV1 = (size_t)B_DIM * H_DIM / 4;   // ssg_in
  const size_t NV2 = NV1;                         // hprev
  const size_t NV3 = (size_t)N1 * K1 / 4;         // W1
  const size_t NV4 = (size_t)N2 * H_DIM / 4;      // W2
  const size_t NV5 = (size_t)H_DIM * H_DIM / 4;   // W3, W4
  const size_t total = NV0 + NV1 + NV2 + NV3 + NV4 + NV5 + NV5;
  const size_t stride = (size_t)gridDim.x * blockDim.x;

  for (size_t v = (size_t)blockIdx.x * blockDim.x + threadIdx.x; v < total; v += stride) {
    size_t idx = v;
    const float* src;
    unsigned short* dst;
    if (idx < NV0) {
      size_t e = idx * 4, b = e >> 11, k = e & 2047;
      src = (k < 1024) ? &x[(b << 10) + k] : &h[(b << 10) + (k - 1024)];
      dst = &combined[e];
    } else if ((idx -= NV0) < NV1) {
      size_t e = idx * 4;
      float4 a = *(const float4*)&ssg_state[e];
      float4 c = *(const float4*)&h[e];
      ushort4 o;
      o.x = f2bf(a.x + c.x); o.y = f2bf(a.y + c.y);
      o.z = f2bf(a.z + c.z); o.w = f2bf(a.w + c.w);
      *(ushort4*)&ssg_in[e] = o;
      continue;
    } else if ((idx -= NV1) < NV2) {
      size_t e = idx * 4; src = &h[e]; dst = &hprev_bf[e];
    } else if ((idx -= NV2) < NV3) {
      size_t e = idx * 4, n = e >> 11, k = e & 2047;
      if (n < 5120) src = (k < 1024) ? &Wx[(n << 10) + k] : &Ux[(n << 10) + (k - 1024)];
      else          src = &a1_w[((n - 5120) << 11) + k];
      dst = &W1[e];
    } else if ((idx -= NV3) < NV4) {
      size_t e = idx * 4, n = e >> 10, k = e & 1023;
      src = (n < 1024) ? &ssg_w[(n << 10) + k] : &r1_w[((n - 1024) << 10) + k];
      dst = &W2[e];
    } else if ((idx -= NV4) < NV5) {
      size_t e = idx * 4; src = &r2_w[e]; dst = &W3[e];
    } else {
      idx -= NV5;
      size_t e = idx * 4; src = &r3_w[e]; dst = &W4[e];
    }
    float4 a = *(const float4*)src;
    ushort4 o;
    o.x = f2bf(a.x); o.y = f2bf(a.y); o.z = f2bf(a.z); o.w = f2bf(a.w);
    *(ushort4*)dst = o;
  }
}

// ---------------------------------------------------------------------------
// 256x256 GEMM, 2-barrier-per-K-tile body (R5 schedule, proven), compute
// switched to mfma_f32_32x32x16_bf16 (this round's single change):
//   per wave: 4 row-blocks x 2 col-blocks of 32x32, K-tile = 4 k-slices of 16
//   -> 32 MFMA/wave/K-tile (was 64 16x16), same LDS traffic, same acc VGPRs.
// Fragment map: A/B row|col = lane&31, k = (lane>>5)*8+i.
// C/D: col = lane&31, row = (reg&3) + 8*(reg>>2) + 4*(lane>>5)  [m74/m101].
// Schedule per K-tile t (same as R5):
//   top: vmcnt(4) [B(t+2) stays in flight] + barrier
//   reads B(ks0,ks1)+A(ks0); STAGE_A(t+1)x2; reads A(ks1); MFMA ks0
//   reads B(ks2,ks3)+A(ks2); MFMA ks1
//   lgkmcnt(0) [all B(t) reads executed] + barrier; STAGE_B(t+2)x2
//   reads A(ks3); MFMA ks2; MFMA ks3
// ---------------------------------------------------------------------------
__global__ __launch_bounds__(512, 2) void gemm8p_mode0(
    const unsigned short* __restrict__ A,
    const unsigned short* __restrict__ W,
    const float* __restrict__ bWx, const float* __restrict__ bUx,
    const float* __restrict__ a1_b,
    unsigned short* __restrict__ gates,
    unsigned short* __restrict__ a_hidden)
{
  __shared__ unsigned short lds[65536];  // 128 KiB

  const int tid  = threadIdx.x;
  const int wave = tid >> 6;
  const int lane = tid & 63;
  const int wm = wave >> 2;      // 0..1 : row half (128 rows)
  const int wn = wave & 3;       // 0..3 : col quarter (64 cols)

  // XCD-aware bijective swizzle (384 % 8 == 0)
  const int NWG = (B_DIM / 256) * (N1 / 256);          // 384
  const int swz = (blockIdx.x & 7) * (NWG / 8) + (blockIdx.x >> 3);
  const int ntn = N1 / 256;                            // 24
  const int tm = swz / ntn, tn = swz % ntn;
  const int tmB = tm * 256, tnB = tn * 256;

  // ---- stage source addressing (pre-swizzled global source, linear dest) ---
  const int sidx = swz1k(lane * 16);
  const int r_l  = sidx >> 6;          // row 0..15 within subtile
  const int kel  = (sidx & 63) >> 1;   // k elem offset (mult of 8)
  const unsigned short* pA[2];
  const unsigned short* pB[2];
#pragma unroll
  for (int j = 0; j < 2; ++j) {
    const int rr = wave * 16 + r_l;
    const int kk0 = j * 32 + kel;
    pA[j] = A + (size_t)(tmB + rr) * K1 + kk0;
    pB[j] = W + (size_t)(tnB + rr) * K1 + kk0;
  }

#define STAGE_A(tt, h_) do { const int p_ = (tt) & 1;                            \
    gload_lds16(pA[0] + (size_t)(h_) * 128 * K1 + (tt) * 64,                     \
                &lds[p_ * 32768 + (h_) * 8192 + (wave * 2 + 0) * 512]);          \
    gload_lds16(pA[1] + (size_t)(h_) * 128 * K1 + (tt) * 64,                     \
                &lds[p_ * 32768 + (h_) * 8192 + (wave * 2 + 1) * 512]); } while (0)
#define STAGE_B(tt, h_) do { const int p_ = (tt) & 1;                            \
    gload_lds16(pB[0] + (size_t)(h_) * 128 * K1 + (tt) * 64,                     \
                &lds[p_ * 32768 + 16384 + (h_) * 8192 + (wave * 2 + 0) * 512]);  \
    gload_lds16(pB[1] + (size_t)(h_) * 128 * K1 + (tt) * 64,                     \
                &lds[p_ * 32768 + 16384 + (h_) * 8192 + (wave * 2 + 1) * 512]); } while (0)

  // ---- per-lane ds_read constants for 32x32 fragments ----
  const int lr = lane & 15;            // row within 16-row subtile
  const int l4 = (lane >> 4) & 1;      // upper/lower 16 of the 32-row block
  const int l5 = lane >> 5;            // k-half selector (k = l5*8 + i)
  const int inner0 = swz1k(lr * 64 + l5 * 16);        // ks even (k&31 in [0,16))
  const int inner1 = swz1k(lr * 64 + 32 + l5 * 16);   // ks odd
  // subtile byte offset for (block b of 32 rows/cols, k-slice ks):
  //   (b*4 + l4*2 + (ks>>1)) * 1024
#define RDA(rb, ks) (*(const bf16x8*)(bA + ((rb) * 4 + l4 * 2 + ((ks) >> 1)) * 1024 \
                                         + (((ks) & 1) ? inner1 : inner0)))
#define RDB(cb, ks) (*(const bf16x8*)(bB + ((cb) * 4 + l4 * 2 + ((ks) >> 1)) * 1024 \
                                         + (((ks) & 1) ? inner1 : inner0)))

  f32x16 acc[4][2];
#pragma unroll
  for (int rb = 0; rb < 4; ++rb)
#pragma unroll
    for (int cb = 0; cb < 2; ++cb)
#pragma unroll
      for (int i = 0; i < 16; ++i) acc[rb][cb][i] = 0.f;

  // prologue: tile0 (A0,A1,B0,B1) + B halves of tile1 -> 12 vmem ops
  STAGE_A(0, 0); STAGE_A(0, 1); STAGE_B(0, 0); STAGE_B(0, 1);
  STAGE_B(1, 0); STAGE_B(1, 1);

#define MFMA8(aV, bV) do {                                                       \
    _Pragma("unroll")                                                            \
    for (int rb = 0; rb < 4; ++rb) {                                             \
      acc[rb][0] = __builtin_amdgcn_mfma_f32_32x32x16_bf16(aV[rb], bV[0],        \
                                                           acc[rb][0], 0, 0, 0); \
      acc[rb][1] = __builtin_amdgcn_mfma_f32_32x32x16_bf16(aV[rb], bV[1],        \
                                                           acc[rb][1], 0, 0, 0); \
    } } while (0)

  const char* lchar = (const char*)lds;
  for (int t = 0; t < NT1; ++t) {
    if (t < NT1 - 1) asm volatile("s_waitcnt vmcnt(4)" ::: "memory");
    else             asm volatile("s_waitcnt vmcnt(0)" ::: "memory");
    __builtin_amdgcn_s_barrier();

    const char* base = lchar + (t & 1) * 65536;
    const char* bA = base + wm * 16384;
    const char* bB = base + 32768 + (wn >> 1) * 16384 + (wn & 1) * 8192;

    bf16x8 bk0[2], bk1[2], bk2[2], bk3[2];
    bf16x8 ak0[4], ak1[4], ak2[4], ak3[4];

    bk0[0] = RDB(0, 0); bk0[1] = RDB(1, 0);
    bk1[0] = RDB(0, 1); bk1[1] = RDB(1, 1);
#pragma unroll
    for (int rb = 0; rb < 4; ++rb) ak0[rb] = RDA(rb, 0);
    if (t + 1 < NT1) { STAGE_A(t + 1, 0); STAGE_A(t + 1, 1); }
#pragma unroll
    for (int rb = 0; rb < 4; ++rb) ak1[rb] = RDA(rb, 1);

    __builtin_amdgcn_s_setprio(1);
    MFMA8(ak0, bk0);
    __builtin_amdgcn_s_setprio(0);

    bk2[0] = RDB(0, 2); bk2[1] = RDB(1, 2);
    bk3[0] = RDB(0, 3); bk3[1] = RDB(1, 3);
#pragma unroll
    for (int rb = 0; rb < 4; ++rb) ak2[rb] = RDA(rb, 2);

    __builtin_amdgcn_s_setprio(1);
    MFMA8(ak1, bk1);
    __builtin_amdgcn_s_setprio(0);

    // all of this wave's B(t) ds_reads executed; sync before B-region DMA
    asm volatile("s_waitcnt lgkmcnt(0)" ::: "memory");
    __builtin_amdgcn_s_barrier();
    if (t + 2 < NT1) { STAGE_B(t + 2, 0); STAGE_B(t + 2, 1); }

#pragma unroll
    for (int rb = 0; rb < 4; ++rb) ak3[rb] = RDA(rb, 3);

    __builtin_amdgcn_s_setprio(1);
    MFMA8(ak2, bk2);
    MFMA8(ak3, bk3);
    __builtin_amdgcn_s_setprio(0);
  }
#undef MFMA8
#undef RDA
#undef RDB
#undef STAGE_A
#undef STAGE_B

  // ---- epilogue: per-wave LDS restage -> coalesced 16B stores ----
  // C frag (rb, cb): col = cb*32 + (lane&31); row = rb*32 + (reg&3) + 8*(reg>>2)
  // + 4*l5. Process in 16-row chunks c (regs 8c..8c+7) through the 2KB slab.
  unsigned short* slab = &lds[wave * 1024];
  const int l31 = lane & 31;
  const int lr8 = lane >> 3, lc8 = lane & 7;
  const bool isgate = (tn < 20);
  const int g = tn >> 2;
  const int colg0 = (isgate ? (tn & 3) : (tn - 20)) * 256 + wn * 64;
  unsigned short* outbase = isgate ? (gates + (size_t)g * ((size_t)B_DIM * 1024))
                                   : a_hidden;
  const int rowg0 = tmB + wm * 128;
  float biasv[2];
#pragma unroll
  for (int cb = 0; cb < 2; ++cb) {
    const int c = colg0 + cb * 32 + l31;
    biasv[cb] = isgate ? (bWx[g * 1024 + c] + bUx[g * 1024 + c]) : a1_b[c];
  }
  __builtin_amdgcn_s_barrier();   // all K-loop LDS traffic fully retired
#pragma unroll
  for (int rb = 0; rb < 4; ++rb) {
#pragma unroll
    for (int c = 0; c < 2; ++c) {
#pragma unroll
      for (int cb = 0; cb < 2; ++cb) {
#pragma unroll
        for (int gg = 0; gg < 2; ++gg) {
#pragma unroll
          for (int j = 0; j < 4; ++j) {
            const int reg = (2 * c + gg) * 4 + j;
            const int row16 = gg * 8 + l5 * 4 + j;
            const float xv = acc[rb][cb][reg] + biasv[cb];
            const float res = isgate ? ((g == 3) ? fast_tanh(xv) : fast_sigmoid(xv))
                                     : fmaxf(xv, 0.f);
            const int colb = ((cb * 32 + l31) * 2) ^ (((row16 >> 2) & 3) << 5);
            slab[(row16 * 128 + colb) >> 1] = f2bf(res);
          }
        }
      }
      asm volatile("s_waitcnt lgkmcnt(0)" ::: "memory");
      __builtin_amdgcn_sched_barrier(0);
#pragma unroll
      for (int rd = 0; rd < 2; ++rd) {
        const int row = rd * 8 + lr8;
        const int cbyte = (lc8 * 16) ^ (((row >> 2) & 3) << 5);
        bf16x8 pk = *(const bf16x8*)((const char*)slab + row * 128 + cbyte);
        const size_t r = (size_t)(rowg0 + rb * 32 + c * 16 + row);
        *(bf16x8*)&outbase[r * 1024 + colg0 + lc8 * 8] = pk;
      }
      asm volatile("s_waitcnt lgkmcnt(0)" ::: "memory");
      __builtin_amdgcn_sched_barrier(0);
    }
  }
}

// ---------------------------------------------------------------------------
// m97-style 128x128 GEMM for the smaller matmuls (R3 known-good version).
// MODE 1: ssg_new (fp32 -> d_out plane2) + r1 (relu->bf16); A per n-region
// MODE 2: r2 = relu(...) -> bf16
// MODE 3: residual (fp32)
// ---------------------------------------------------------------------------
template <int MODE>
__global__ __launch_bounds__(256, 3) void gemm_bf16(
    const unsigned short* __restrict__ A0g,
    const unsigned short* __restrict__ A1g,
    const unsigned short* __restrict__ Wg,
    const int M, const int N, const int K,
    const float* __restrict__ b0, const float* __restrict__ b1,
    void* __restrict__ out0, void* __restrict__ out1)
{
  __shared__ unsigned short As[128 * 64];
  __shared__ unsigned short Bs[128 * 64];

  const int tid  = threadIdx.x;
  const int wave = tid >> 6;
  const int lane = tid & 63;
  const int wm = wave >> 1, wn = wave & 1;

  const int ntn = N >> 7;
  const int tm = blockIdx.x / ntn;
  const int tn = blockIdx.x % ntn;

  const unsigned short* Ag = A0g;
  if (MODE == 1 && tn >= 8) Ag = A1g;  // n >= 1024 region uses h_prev

  const int lrow = lane >> 3;
  const int lk   = (lane & 7) * 8;
  size_t a_off[4], b_off[4];
#pragma unroll
  for (int i = 0; i < 4; ++i) {
    int c = wave * 4 + i;
    int row = c * 8 + lrow;
    a_off[i] = (size_t)(tm * 128 + row) * K + lk;
    b_off[i] = (size_t)(tn * 128 + row) * K + lk;
  }

  f32x4 acc[4][4];
#pragma unroll
  for (int m = 0; m < 4; ++m)
#pragma unroll
    for (int n = 0; n < 4; ++n) acc[m][n] = (f32x4){0.f, 0.f, 0.f, 0.f};

  const int arow  = wm * 64 + (lane & 15);
  const int brow  = wn * 64 + (lane & 15);
  const int kfrag = (lane >> 4) * 8;

  for (int k0 = 0; k0 < K; k0 += 64) {
#pragma unroll
    for (int i = 0; i < 4; ++i) {
      gload_lds16(Ag + a_off[i] + k0, &As[(wave * 4 + i) * 512]);
      gload_lds16(Wg + b_off[i] + k0, &Bs[(wave * 4 + i) * 512]);
    }
    __syncthreads();
#pragma unroll
    for (int kk = 0; kk < 2; ++kk) {
      bf16x8 af[4], bfr[4];
#pragma unroll
      for (int m = 0; m < 4; ++m)
        af[m] = *(const bf16x8*)&As[(arow + m * 16) * 64 + kk * 32 + kfrag];
#pragma unroll
      for (int n = 0; n < 4; ++n)
        bfr[n] = *(const bf16x8*)&Bs[(brow + n * 16) * 64 + kk * 32 + kfrag];
#pragma unroll
      for (int m = 0; m < 4; ++m)
#pragma unroll
        for (int n = 0; n < 4; ++n)
          acc[m][n] = __builtin_amdgcn_mfma_f32_16x16x32_bf16(
              af[m], bfr[n], acc[m][n], 0, 0, 0);
    }
    __syncthreads();
  }

  const int col0 = tn * 128 + wn * 64;
  const int row0 = tm * 128 + wm * 64 + ((lane >> 4) << 2);
#pragma unroll
  for (int n = 0; n < 4; ++n) {
    const int col = col0 + n * 16 + (lane & 15);
    float bias;
    if (MODE == 1)      bias = (col < 1024) ? b0[col] : b1[col - 1024];
    else                bias = b0[col];
#pragma unroll
    for (int m = 0; m < 4; ++m) {
      const int rowb = row0 + m * 16;
      f32x4 v = acc[m][n];
#pragma unroll
      for (int j = 0; j < 4; ++j) {
        const float xv = v[j] + bias;
        const int r = rowb + j;
        if (MODE == 1) {
          if (col < 1024) {
            ((float*)out0)[(size_t)r * 1024 + col] = xv;             // ssg_new fp32
          } else {
            ((unsigned short*)out1)[(size_t)r * 1024 + (col - 1024)] = f2bf(fmaxf(xv, 0.f));
          }
        } else if (MODE == 2) {
          ((unsigned short*)out0)[(size_t)r * 1024 + col] = f2bf(fmaxf(xv, 0.f));
        } else {
          ((float*)out0)[(size_t)r * 1024 + col] = xv;               // residual fp32
        }
      }
    }
  }
}

// ---------------------------------------------------------------------------
// alpha GEMV
// ---------------------------------------------------------------------------
__global__ __launch_bounds__(256) void alpha_kernel(
    const unsigned short* __restrict__ a_hidden,
    const float* __restrict__ a2_w, const float* __restrict__ a2_b,
    float* __restrict__ alpha)
{
  const int wave = threadIdx.x >> 6, lane = threadIdx.x & 63;
  const int row = blockIdx.x * 4 + wave;
  const unsigned short* ah = a_hidden + (size_t)row * 1024;
  float sum = 0.f;
#pragma unroll
  for (int half = 0; half < 2; ++half) {
    const int h0 = half * 512 + lane * 8;
    ushort4 u0 = *(const ushort4*)&ah[h0];
    ushort4 u1 = *(const ushort4*)&ah[h0 + 4];
    float4 w0 = *(const float4*)&a2_w[h0];
    float4 w1 = *(const float4*)&a2_w[h0 + 4];
    sum += bf2f(u0.x) * w0.x + bf2f(u0.y) * w0.y + bf2f(u0.z) * w0.z + bf2f(u0.w) * w0.w;
    sum += bf2f(u1.x) * w1.x + bf2f(u1.y) * w1.y + bf2f(u1.z) * w1.z + bf2f(u1.w) * w1.w;
  }
#pragma unroll
  for (int off = 32; off; off >>= 1) sum += __shfl_xor(sum, off);
  if (lane == 0) alpha[row] = fast_sigmoid(sum + a2_b[0]);
}

// ---------------------------------------------------------------------------
// final elementwise (high-occupancy vec4 streaming)
// ---------------------------------------------------------------------------
__global__ __launch_bounds__(256) void final_elem_kernel(
    const unsigned short* __restrict__ gates,
    const float* __restrict__ c_prev,
    const float* __restrict__ alpha,
    const float* __restrict__ residual,
    const float* __restrict__ ssg_new,
    float* __restrict__ h_out, float* __restrict__ c_out)
{
  const size_t BH = (size_t)B_DIM * H_DIM;
  const size_t e = ((size_t)blockIdx.x * blockDim.x + threadIdx.x) * 4;
  if (e >= BH) return;
  const float al = alpha[e >> 10];
  ushort4 iu = *(const ushort4*)&gates[e];
  ushort4 fu = *(const ushort4*)&gates[BH + e];
  ushort4 ou = *(const ushort4*)&gates[2 * BH + e];
  ushort4 cu = *(const ushort4*)&gates[3 * BH + e];
  ushort4 su = *(const ushort4*)&gates[4 * BH + e];
  float4 cp = *(const float4*)&c_prev[e];
  float4 rs = *(const float4*)&residual[e];
  float4 sg = *(const float4*)&ssg_new[e];
  float4 ho, co;
  co.x = bf2f(fu.x) * cp.x + bf2f(iu.x) * bf2f(cu.x) * bf2f(su.x) * al * sg.x + rs.x;
  co.y = bf2f(fu.y) * cp.y + bf2f(iu.y) * bf2f(cu.y) * bf2f(su.y) * al * sg.y + rs.y;
  co.z = bf2f(fu.z) * cp.z + bf2f(iu.z) * bf2f(cu.z) * bf2f(su.z) * al * sg.z + rs.z;
  co.w = bf2f(fu.w) * cp.w + bf2f(iu.w) * bf2f(cu.w) * bf2f(su.w) * al * sg.w + rs.w;
  ho.x = bf2f(ou.x) * fast_tanh(co.x);
  ho.y = bf2f(ou.y) * fast_tanh(co.y);
  ho.z = bf2f(ou.z) * fast_tanh(co.z);
  ho.w = bf2f(ou.w) * fast_tanh(co.w);
  *(float4*)&h_out[e] = ho;
  *(float4*)&c_out[e] = co;
}

// ---------------------------------------------------------------------------
extern "C" void kernel_launch(void* const* d_in, const int* in_sizes, int n_in,
                              void* d_out, int out_size, void* d_ws, size_t ws_size,
                              hipStream_t stream)
{
  (void)in_sizes; (void)n_in; (void)out_size; (void)ws_size;
  const float* x         = (const float*)d_in[0];
  const float* h_prev    = (const float*)d_in[1];
  const float* c_prev    = (const float*)d_in[2];
  const float* ssg_state = (const float*)d_in[3];
  const float* Wx        = (const float*)d_in[4];
  const float* bWx       = (const float*)d_in[5];
  const float* Ux        = (const float*)d_in[6];
  const float* bUx       = (const float*)d_in[7];
  const float* a1_w      = (const float*)d_in[8];
  const float* a1_b      = (const float*)d_in[9];
  const float* a2_w      = (const float*)d_in[10];
  const float* a2_b      = (const float*)d_in[11];
  const float* r1_w      = (const float*)d_in[12];
  const float* r1_b      = (const float*)d_in[13];
  const float* r2_w      = (const float*)d_in[14];
  const float* r2_b      = (const float*)d_in[15];
  const float* r3_w      = (const float*)d_in[16];
  const float* r3_b      = (const float*)d_in[17];
  const float* ssg_w     = (const float*)d_in[18];
  const float* ssg_b     = (const float*)d_in[19];

  char* ws = (char*)d_ws;
  unsigned short* combined = (unsigned short*)(ws);               // 16,777,216
  unsigned short* ssg_in   = (unsigned short*)(ws + 16777216);    //  8,388,608
  unsigned short* hprev_bf = (unsigned short*)(ws + 25165824);    //  8,388,608
  unsigned short* W1       = (unsigned short*)(ws + 33554432);    // 25,165,824
  unsigned short* W2       = (unsigned short*)(ws + 58720256);    //  4,194,304
  unsigned short* W3       = (unsigned short*)(ws + 62914560);    //  2,097,152
  unsigned short* W4       = (unsigned short*)(ws + 65011712);    //  2,097,152
  unsigned short* gates    = (unsigned short*)(ws + 67108864);    // 41,943,040
  unsigned short* a_hidden = (unsigned short*)(ws + 109051904);   //  8,388,608
  float*          alpha    = (float*)(ws + 117440512);            //     16,384
  unsigned short* r1       = (unsigned short*)(ws + 117456896);   //  8,388,608
  unsigned short* r2       = (unsigned short*)(ws + 125845504);   //  8,388,608
  float*          residual = (float*)(ws + 134234112);            // 16,777,216

  float* h_out   = (float*)d_out;
  float* c_out   = h_out + (size_t)B_DIM * H_DIM;
  float* ssg_out = c_out + (size_t)B_DIM * H_DIM;

  prep_kernel<<<4096, 256, 0, stream>>>(x, h_prev, ssg_state, Wx, Ux, a1_w,
                                        ssg_w, r1_w, r2_w, r3_w,
                                        combined, ssg_in, hprev_bf, W1, W2, W3, W4);

  gemm8p_mode0<<<(B_DIM / 256) * (N1 / 256), 512, 0, stream>>>(
      combined, W1, bWx, bUx, a1_b, gates, a_hidden);

  gemm_bf16<1><<<(B_DIM / 128) * (N2 / 128), 256, 0, stream>>>(
      ssg_in, hprev_bf, W2, B_DIM, N2, 1024, ssg_b, r1_b, ssg_out, r1);

  gemm_bf16<2><<<(B_DIM / 128) * (1024 / 128), 256, 0, stream>>>(
      r1, r1, W3, B_DIM, 1024, 1024, r2_b, nullptr, r2, nullptr);

  gemm_bf16<3><<<(B_DIM / 128) * (1024 / 128), 256, 0, stream>>>(
      r2, r2, W4, B_DIM, 1024, 1024, r3_b, nullptr, residual, nullptr);

  alpha_kernel<<<B_DIM / 4, 256, 0, stream>>>(a_hidden, a2_w, a2_b, alpha);

  final_elem_kernel<<<(B_DIM * H_DIM / 4) / 256, 256, 0, stream>>>(
      gates, c_prev, alpha, residual, ssg_out, h_out, c_out);
}

// Round 7
// 266.581 us; speedup vs baseline: 1.0500x; 1.0500x over previous
//
#include <hip/hip_runtime.h>
#include <hip/hip_bf16.h>

// Problem constants
#define B_DIM 4096
#define H_DIM 1024
#define K1    2048   // IN + H
#define N1    6144   // 5 gates * 1024 + a1 (1024)
#define N2    2048   // ssg (1024) + r1 (1024)
#define NT1   (K1 / 64)   // 32 K-tiles for the big GEMM

typedef __attribute__((ext_vector_type(8))) short bf16x8;
typedef __attribute__((ext_vector_type(4))) float f32x4;

__device__ __forceinline__ unsigned short f2bf(float f) {
  unsigned int x = __float_as_uint(f);
  x += 0x7fffu + ((x >> 16) & 1u);   // RTNE
  return (unsigned short)(x >> 16);
}
__device__ __forceinline__ float bf2f(unsigned short u) {
  return __uint_as_float(((unsigned int)u) << 16);
}
__device__ __forceinline__ float fast_sigmoid(float x) {
  return __builtin_amdgcn_rcpf(1.0f + __expf(-x));
}
__device__ __forceinline__ float fast_tanh(float x) {
  return 1.0f - 2.0f * __builtin_amdgcn_rcpf(1.0f + __expf(2.0f * x));
}
__device__ __forceinline__ void gload_lds16(const void* g, void* l) {
  __builtin_amdgcn_global_load_lds(
      (const __attribute__((address_space(1))) void*)g,
      (__attribute__((address_space(3))) void*)l, 16, 0, 0);
}

// m201's st_16x32 swizzle: XOR byte-bit5 with bit9 within a 1024B subtile.
__device__ __forceinline__ int swz1k(int x) {
  return x ^ (((x >> 9) & 1) << 5);
}

// ---------------------------------------------------------------------------
// prep: build bf16 activations + weight panels in workspace (grid-stride vec4)
// ---------------------------------------------------------------------------
__global__ __launch_bounds__(256) void prep_kernel(
    const float* __restrict__ x, const float* __restrict__ h,
    const float* __restrict__ ssg_state,
    const float* __restrict__ Wx, const float* __restrict__ Ux,
    const float* __restrict__ a1_w,
    const float* __restrict__ ssg_w, const float* __restrict__ r1_w,
    const float* __restrict__ r2_w, const float* __restrict__ r3_w,
    unsigned short* __restrict__ combined,
    unsigned short* __restrict__ ssg_in,
    unsigned short* __restrict__ hprev_bf,
    unsigned short* __restrict__ W1,
    unsigned short* __restrict__ W2,
    unsigned short* __restrict__ W3,
    unsigned short* __restrict__ W4)
{
  const size_t NV0 = (size_t)B_DIM * K1 / 4;      // combined
  const size_t NV1 = (size_t)B_DIM * H_DIM / 4;   // ssg_in
  const size_t NV2 = NV1;                         // hprev
  const size_t NV3 = (size_t)N1 * K1 / 4;         // W1
  const size_t NV4 = (size_t)N2 * H_DIM / 4;      // W2
  const size_t NV5 = (size_t)H_DIM * H_DIM / 4;   // W3, W4
  const size_t total = NV0 + NV1 + NV2 + NV3 + NV4 + NV5 + NV5;
  const size_t stride = (size_t)gridDim.x * blockDim.x;

  for (size_t v = (size_t)blockIdx.x * blockDim.x + threadIdx.x; v < total; v += stride) {
    size_t idx = v;
    const float* src;
    unsigned short* dst;
    if (idx < NV0) {
      size_t e = idx * 4, b = e >> 11, k = e & 2047;
      src = (k < 1024) ? &x[(b << 10) + k] : &h[(b << 10) + (k - 1024)];
      dst = &combined[e];
    } else if ((idx -= NV0) < NV1) {
      size_t e = idx * 4;
      float4 a = *(const float4*)&ssg_state[e];
      float4 c = *(const float4*)&h[e];
      ushort4 o;
      o.x = f2bf(a.x + c.x); o.y = f2bf(a.y + c.y);
      o.z = f2bf(a.z + c.z); o.w = f2bf(a.w + c.w);
      *(ushort4*)&ssg_in[e] = o;
      continue;
    } else if ((idx -= NV1) < NV2) {
      size_t e = idx * 4; src = &h[e]; dst = &hprev_bf[e];
    } else if ((idx -= NV2) < NV3) {
      size_t e = idx * 4, n = e >> 11, k = e & 2047;
      if (n < 5120) src = (k < 1024) ? &Wx[(n << 10) + k] : &Ux[(n << 10) + (k - 1024)];
      else          src = &a1_w[((n - 5120) << 11) + k];
      dst = &W1[e];
    } else if ((idx -= NV3) < NV4) {
      size_t e = idx * 4, n = e >> 10, k = e & 1023;
      src = (n < 1024) ? &ssg_w[(n << 10) + k] : &r1_w[((n - 1024) << 10) + k];
      dst = &W2[e];
    } else if ((idx -= NV4) < NV5) {
      size_t e = idx * 4; src = &r2_w[e]; dst = &W3[e];
    } else {
      idx -= NV5;
      size_t e = idx * 4; src = &r3_w[e]; dst = &W4[e];
    }
    float4 a = *(const float4*)src;
    ushort4 o;
    o.x = f2bf(a.x); o.y = f2bf(a.y); o.z = f2bf(a.z); o.w = f2bf(a.w);
    *(ushort4*)dst = o;
  }
}

// ---------------------------------------------------------------------------
// 128x256 GEMM (BM=128 halves R5's 256), 2-barrier-per-K-tile body, 16x16x32
// MFMA (R5's verified conflict-free read pattern). Grid = 32x24 = 768 blocks
// = exactly 3 full rounds of 256 CUs (R5's 384 = 1.5 rounds, 75% util).
// 8 waves: wm = wave>>2 (2 row halves of 64), wn = wave&3 (4 col quarters
// of 64). Per wave 64x64 out = 4x4 frags; 32 MFMA/wave/K-tile.
// LDS 96KB: 2 x [A 128x64 (16KB) | B 256x64 (32KB)] in 1KB 16x32-elem
// subtiles, swz1k both sides.
// Schedule per K-tile t:
//   top: vmcnt(4) [B(t+2) in flight] + barrier
//   reads b0,a0 (kq0); STAGE_A(t+1) [2 ops]; reads b1,a1 (kq1)
//   MFMA(a0,b0); lgkmcnt(0)+barrier [B(t) reads done]; STAGE_B(t+2) [4 ops]
//   MFMA(a1,b1)
// vmcnt audit: at top of t: in-flight = A(t)2? no -- A(t) issued t-1 early,
// B(t) issued t-2 mid, A(t+1)/B(t+2) not yet issued; outstanding after the
// 4 newest (B(t+1)) are drained = A(t),B(t) complete. Prologue = 10 ops.
// ---------------------------------------------------------------------------
__global__ __launch_bounds__(512, 2) void gemm8p_mode0(
    const unsigned short* __restrict__ A,
    const unsigned short* __restrict__ W,
    const float* __restrict__ bWx, const float* __restrict__ bUx,
    const float* __restrict__ a1_b,
    unsigned short* __restrict__ gates,
    unsigned short* __restrict__ a_hidden)
{
  __shared__ unsigned short lds[49152];  // 96 KiB: 2 buffers x 24576 shorts

  const int tid  = threadIdx.x;
  const int wave = tid >> 6;
  const int lane = tid & 63;
  const int wm = wave >> 2;      // 0..1 : row half (64 rows)
  const int wn = wave & 3;       // 0..3 : col quarter (64 cols)

  // XCD-aware bijective swizzle (768 % 8 == 0, cpx = 96)
  const int NWG = (B_DIM / 128) * (N1 / 256);          // 768
  const int swz = (blockIdx.x & 7) * (NWG / 8) + (blockIdx.x >> 3);
  const int ntn = N1 / 256;                            // 24
  const int tm = swz / ntn, tn = swz % ntn;
  const int tmB = tm * 128, tnB = tn * 256;

  // ---- stage source addressing (pre-swizzled global source, linear dest) ---
  const int sidx = swz1k(lane * 16);
  const int r_l  = sidx >> 6;          // row 0..15 within subtile
  const int kel  = (sidx & 63) >> 1;   // k elem offset (mult of 8)
  const unsigned short* pA[2];
  const unsigned short* pB[2];
#pragma unroll
  for (int j = 0; j < 2; ++j) {
    const int rr = wave * 16 + r_l;
    const int kk0 = j * 32 + kel;
    pA[j] = A + (size_t)(tmB + rr) * K1 + kk0;   // A tile rows 0..127
    pB[j] = W + (size_t)(tnB + rr) * K1 + kk0;   // B rows (cols of C)
  }

  // LDS (shorts): buffer p at p*24576; A at +0 (8192), B at +8192 (16384)
#define STAGE_A(tt) do { const int p_ = (tt) & 1;                                \
    gload_lds16(pA[0] + (size_t)(tt) * 64,                                       \
                &lds[p_ * 24576 + (wave * 2 + 0) * 512]);                        \
    gload_lds16(pA[1] + (size_t)(tt) * 64,                                       \
                &lds[p_ * 24576 + (wave * 2 + 1) * 512]); } while (0)
#define STAGE_B(tt, h_) do { const int p_ = (tt) & 1;                            \
    gload_lds16(pB[0] + (size_t)(h_) * 128 * K1 + (tt) * 64,                     \
                &lds[p_ * 24576 + 8192 + (h_) * 8192 + (wave * 2 + 0) * 512]);   \
    gload_lds16(pB[1] + (size_t)(h_) * 128 * K1 + (tt) * 64,                     \
                &lds[p_ * 24576 + 8192 + (h_) * 8192 + (wave * 2 + 1) * 512]); } while (0)

  // ---- ds_read addressing (R5-verified conflict-free 16x16 pattern) ----
  const int loc = swz1k((lane & 15) * 64 + (lane >> 4) * 16);

  f32x4 acc[4][4];
#pragma unroll
  for (int m = 0; m < 4; ++m)
#pragma unroll
    for (int n = 0; n < 4; ++n) acc[m][n] = (f32x4){0.f, 0.f, 0.f, 0.f};

  // prologue: A(0), B(0) both halves, B(1) both halves -> 10 vmem ops
  STAGE_A(0); STAGE_B(0, 0); STAGE_B(0, 1);
  STAGE_B(1, 0); STAGE_B(1, 1);

#define MFMA16(aV, bV) do {                                                      \
    _Pragma("unroll")                                                            \
    for (int n = 0; n < 4; ++n) {                                                \
      _Pragma("unroll")                                                          \
      for (int m = 0; m < 4; ++m)                                                \
        acc[m][n] = __builtin_amdgcn_mfma_f32_16x16x32_bf16(                     \
            aV[m], bV[n], acc[m][n], 0, 0, 0);                                   \
    } } while (0)

  const char* lchar = (const char*)lds;
  for (int t = 0; t < NT1; ++t) {
    if (t < NT1 - 1) asm volatile("s_waitcnt vmcnt(4)" ::: "memory");
    else             asm volatile("s_waitcnt vmcnt(0)" ::: "memory");
    __builtin_amdgcn_s_barrier();

    const char* base = lchar + (t & 1) * 49152;
    const char* bA = base + wm * 8192 + loc;           // 4 subtile-pairs
    const char* bB = base + 16384 + wn * 8192 + loc;   // 4 subtile-pairs

    bf16x8 a0[4], a1[4], b0[4], b1[4];
#pragma unroll
    for (int n = 0; n < 4; ++n) b0[n] = *(const bf16x8*)(bB + (2 * n + 0) * 1024);
#pragma unroll
    for (int m = 0; m < 4; ++m) a0[m] = *(const bf16x8*)(bA + (2 * m + 0) * 1024);
    if (t + 1 < NT1) STAGE_A(t + 1);
#pragma unroll
    for (int n = 0; n < 4; ++n) b1[n] = *(const bf16x8*)(bB + (2 * n + 1) * 1024);
#pragma unroll
    for (int m = 0; m < 4; ++m) a1[m] = *(const bf16x8*)(bA + (2 * m + 1) * 1024);

    __builtin_amdgcn_s_setprio(1);
    MFMA16(a0, b0);
    __builtin_amdgcn_s_setprio(0);

    // all of this wave's B(t) ds_reads executed; sync before B-region DMA
    asm volatile("s_waitcnt lgkmcnt(0)" ::: "memory");
    __builtin_amdgcn_s_barrier();
    if (t + 2 < NT1) { STAGE_B(t + 2, 0); STAGE_B(t + 2, 1); }

    __builtin_amdgcn_s_setprio(1);
    MFMA16(a1, b1);
    __builtin_amdgcn_s_setprio(0);
  }
#undef MFMA16
#undef STAGE_A
#undef STAGE_B

  // ---- epilogue: per-wave LDS restage -> coalesced 16B stores ----
  unsigned short* slab = &lds[wave * 1024];
  const int l15 = lane & 15, lq4 = (lane >> 4) << 2;
  const int lr8 = lane >> 3, lc8 = lane & 7;
  const bool isgate = (tn < 20);
  const int g = tn >> 2;
  const int colg0 = (isgate ? (tn & 3) : (tn - 20)) * 256 + wn * 64;
  unsigned short* outbase = isgate ? (gates + (size_t)g * ((size_t)B_DIM * 1024))
                                   : a_hidden;
  const int rowg0 = tmB + wm * 64;
  float biasv[4];
#pragma unroll
  for (int fn = 0; fn < 4; ++fn) {
    const int c = colg0 + fn * 16 + l15;
    biasv[fn] = isgate ? (bWx[g * 1024 + c] + bUx[g * 1024 + c]) : a1_b[c];
  }
  __builtin_amdgcn_s_barrier();   // all K-loop LDS traffic fully retired
#pragma unroll
  for (int fm = 0; fm < 4; ++fm) {
#pragma unroll
    for (int fn = 0; fn < 4; ++fn) {
      f32x4 v = acc[fm][fn];
#pragma unroll
      for (int j = 0; j < 4; ++j) {
        const int row = lq4 + j;
        const float xv = v[j] + biasv[fn];
        const float res = isgate ? ((g == 3) ? fast_tanh(xv) : fast_sigmoid(xv))
                                 : fmaxf(xv, 0.f);
        const int colb = ((fn * 16 + l15) * 2) ^ (((row >> 2) & 3) << 5);
        slab[(row * 128 + colb) >> 1] = f2bf(res);
      }
    }
    asm volatile("s_waitcnt lgkmcnt(0)" ::: "memory");
    __builtin_amdgcn_sched_barrier(0);
#pragma unroll
    for (int rd = 0; rd < 2; ++rd) {
      const int row = rd * 8 + lr8;
      const int cb = (lc8 * 16) ^ (((row >> 2) & 3) << 5);
      bf16x8 pk = *(const bf16x8*)((const char*)slab + row * 128 + cb);
      const size_t r = (size_t)(rowg0 + fm * 16 + row);
      *(bf16x8*)&outbase[r * 1024 + colg0 + lc8 * 8] = pk;
    }
    asm volatile("s_waitcnt lgkmcnt(0)" ::: "memory");
    __builtin_amdgcn_sched_barrier(0);
  }
}

// ---------------------------------------------------------------------------
// m97-style 128x128 GEMM for the smaller matmuls (R3 known-good version).
// MODE 1: ssg_new (fp32 -> d_out plane2) + r1 (relu->bf16); A per n-region
// MODE 2: r2 = relu(...) -> bf16
// MODE 3: residual (fp32)
// ---------------------------------------------------------------------------
template <int MODE>
__global__ __launch_bounds__(256, 3) void gemm_bf16(
    const unsigned short* __restrict__ A0g,
    const unsigned short* __restrict__ A1g,
    const unsigned short* __restrict__ Wg,
    const int M, const int N, const int K,
    const float* __restrict__ b0, const float* __restrict__ b1,
    void* __restrict__ out0, void* __restrict__ out1)
{
  __shared__ unsigned short As[128 * 64];
  __shared__ unsigned short Bs[128 * 64];

  const int tid  = threadIdx.x;
  const int wave = tid >> 6;
  const int lane = tid & 63;
  const int wm = wave >> 1, wn = wave & 1;

  const int ntn = N >> 7;
  const int tm = blockIdx.x / ntn;
  const int tn = blockIdx.x % ntn;

  const unsigned short* Ag = A0g;
  if (MODE == 1 && tn >= 8) Ag = A1g;  // n >= 1024 region uses h_prev

  const int lrow = lane >> 3;
  const int lk   = (lane & 7) * 8;
  size_t a_off[4], b_off[4];
#pragma unroll
  for (int i = 0; i < 4; ++i) {
    int c = wave * 4 + i;
    int row = c * 8 + lrow;
    a_off[i] = (size_t)(tm * 128 + row) * K + lk;
    b_off[i] = (size_t)(tn * 128 + row) * K + lk;
  }

  f32x4 acc[4][4];
#pragma unroll
  for (int m = 0; m < 4; ++m)
#pragma unroll
    for (int n = 0; n < 4; ++n) acc[m][n] = (f32x4){0.f, 0.f, 0.f, 0.f};

  const int arow  = wm * 64 + (lane & 15);
  const int brow  = wn * 64 + (lane & 15);
  const int kfrag = (lane >> 4) * 8;

  for (int k0 = 0; k0 < K; k0 += 64) {
#pragma unroll
    for (int i = 0; i < 4; ++i) {
      gload_lds16(Ag + a_off[i] + k0, &As[(wave * 4 + i) * 512]);
      gload_lds16(Wg + b_off[i] + k0, &Bs[(wave * 4 + i) * 512]);
    }
    __syncthreads();
#pragma unroll
    for (int kk = 0; kk < 2; ++kk) {
      bf16x8 af[4], bfr[4];
#pragma unroll
      for (int m = 0; m < 4; ++m)
        af[m] = *(const bf16x8*)&As[(arow + m * 16) * 64 + kk * 32 + kfrag];
#pragma unroll
      for (int n = 0; n < 4; ++n)
        bfr[n] = *(const bf16x8*)&Bs[(brow + n * 16) * 64 + kk * 32 + kfrag];
#pragma unroll
      for (int m = 0; m < 4; ++m)
#pragma unroll
        for (int n = 0; n < 4; ++n)
          acc[m][n] = __builtin_amdgcn_mfma_f32_16x16x32_bf16(
              af[m], bfr[n], acc[m][n], 0, 0, 0);
    }
    __syncthreads();
  }

  const int col0 = tn * 128 + wn * 64;
  const int row0 = tm * 128 + wm * 64 + ((lane >> 4) << 2);
#pragma unroll
  for (int n = 0; n < 4; ++n) {
    const int col = col0 + n * 16 + (lane & 15);
    float bias;
    if (MODE == 1)      bias = (col < 1024) ? b0[col] : b1[col - 1024];
    else                bias = b0[col];
#pragma unroll
    for (int m = 0; m < 4; ++m) {
      const int rowb = row0 + m * 16;
      f32x4 v = acc[m][n];
#pragma unroll
      for (int j = 0; j < 4; ++j) {
        const float xv = v[j] + bias;
        const int r = rowb + j;
        if (MODE == 1) {
          if (col < 1024) {
            ((float*)out0)[(size_t)r * 1024 + col] = xv;             // ssg_new fp32
          } else {
            ((unsigned short*)out1)[(size_t)r * 1024 + (col - 1024)] = f2bf(fmaxf(xv, 0.f));
          }
        } else if (MODE == 2) {
          ((unsigned short*)out0)[(size_t)r * 1024 + col] = f2bf(fmaxf(xv, 0.f));
        } else {
          ((float*)out0)[(size_t)r * 1024 + col] = xv;               // residual fp32
        }
      }
    }
  }
}

// ---------------------------------------------------------------------------
// alpha GEMV
// ---------------------------------------------------------------------------
__global__ __launch_bounds__(256) void alpha_kernel(
    const unsigned short* __restrict__ a_hidden,
    const float* __restrict__ a2_w, const float* __restrict__ a2_b,
    float* __restrict__ alpha)
{
  const int wave = threadIdx.x >> 6, lane = threadIdx.x & 63;
  const int row = blockIdx.x * 4 + wave;
  const unsigned short* ah = a_hidden + (size_t)row * 1024;
  float sum = 0.f;
#pragma unroll
  for (int half = 0; half < 2; ++half) {
    const int h0 = half * 512 + lane * 8;
    ushort4 u0 = *(const ushort4*)&ah[h0];
    ushort4 u1 = *(const ushort4*)&ah[h0 + 4];
    float4 w0 = *(const float4*)&a2_w[h0];
    float4 w1 = *(const float4*)&a2_w[h0 + 4];
    sum += bf2f(u0.x) * w0.x + bf2f(u0.y) * w0.y + bf2f(u0.z) * w0.z + bf2f(u0.w) * w0.w;
    sum += bf2f(u1.x) * w1.x + bf2f(u1.y) * w1.y + bf2f(u1.z) * w1.z + bf2f(u1.w) * w1.w;
  }
#pragma unroll
  for (int off = 32; off; off >>= 1) sum += __shfl_xor(sum, off);
  if (lane == 0) alpha[row] = fast_sigmoid(sum + a2_b[0]);
}

// ---------------------------------------------------------------------------
// final elementwise (high-occupancy vec4 streaming)
// ---------------------------------------------------------------------------
__global__ __launch_bounds__(256) void final_elem_kernel(
    const unsigned short* __restrict__ gates,
    const float* __restrict__ c_prev,
    const float* __restrict__ alpha,
    const float* __restrict__ residual,
    const float* __restrict__ ssg_new,
    float* __restrict__ h_out, float* __restrict__ c_out)
{
  const size_t BH = (size_t)B_DIM * H_DIM;
  const size_t e = ((size_t)blockIdx.x * blockDim.x + threadIdx.x) * 4;
  if (e >= BH) return;
  const float al = alpha[e >> 10];
  ushort4 iu = *(const ushort4*)&gates[e];
  ushort4 fu = *(const ushort4*)&gates[BH + e];
  ushort4 ou = *(const ushort4*)&gates[2 * BH + e];
  ushort4 cu = *(const ushort4*)&gates[3 * BH + e];
  ushort4 su = *(const ushort4*)&gates[4 * BH + e];
  float4 cp = *(const float4*)&c_prev[e];
  float4 rs = *(const float4*)&residual[e];
  float4 sg = *(const float4*)&ssg_new[e];
  float4 ho, co;
  co.x = bf2f(fu.x) * cp.x + bf2f(iu.x) * bf2f(cu.x) * bf2f(su.x) * al * sg.x + rs.x;
  co.y = bf2f(fu.y) * cp.y + bf2f(iu.y) * bf2f(cu.y) * bf2f(su.y) * al * sg.y + rs.y;
  co.z = bf2f(fu.z) * cp.z + bf2f(iu.z) * bf2f(cu.z) * bf2f(su.z) * al * sg.z + rs.z;
  co.w = bf2f(fu.w) * cp.w + bf2f(iu.w) * bf2f(cu.w) * bf2f(su.w) * al * sg.w + rs.w;
  ho.x = bf2f(ou.x) * fast_tanh(co.x);
  ho.y = bf2f(ou.y) * fast_tanh(co.y);
  ho.z = bf2f(ou.z) * fast_tanh(co.z);
  ho.w = bf2f(ou.w) * fast_tanh(co.w);
  *(float4*)&h_out[e] = ho;
  *(float4*)&c_out[e] = co;
}

// ---------------------------------------------------------------------------
extern "C" void kernel_launch(void* const* d_in, const int* in_sizes, int n_in,
                              void* d_out, int out_size, void* d_ws, size_t ws_size,
                              hipStream_t stream)
{
  (void)in_sizes; (void)n_in; (void)out_size; (void)ws_size;
  const float* x         = (const float*)d_in[0];
  const float* h_prev    = (const float*)d_in[1];
  const float* c_prev    = (const float*)d_in[2];
  const float* ssg_state = (const float*)d_in[3];
  const float* Wx        = (const float*)d_in[4];
  const float* bWx       = (const float*)d_in[5];
  const float* Ux        = (const float*)d_in[6];
  const float* bUx       = (const float*)d_in[7];
  const float* a1_w      = (const float*)d_in[8];
  const float* a1_b      = (const float*)d_in[9];
  const float* a2_w      = (const float*)d_in[10];
  const float* a2_b      = (const float*)d_in[11];
  const float* r1_w      = (const float*)d_in[12];
  const float* r1_b      = (const float*)d_in[13];
  const float* r2_w      = (const float*)d_in[14];
  const float* r2_b      = (const float*)d_in[15];
  const float* r3_w      = (const float*)d_in[16];
  const float* r3_b      = (const float*)d_in[17];
  const float* ssg_w     = (const float*)d_in[18];
  const float* ssg_b     = (const float*)d_in[19];

  char* ws = (char*)d_ws;
  unsigned short* combined = (unsigned short*)(ws);               // 16,777,216
  unsigned short* ssg_in   = (unsigned short*)(ws + 16777216);    //  8,388,608
  unsigned short* hprev_bf = (unsigned short*)(ws + 25165824);    //  8,388,608
  unsigned short* W1       = (unsigned short*)(ws + 33554432);    // 25,165,824
  unsigned short* W2       = (unsigned short*)(ws + 58720256);    //  4,194,304
  unsigned short* W3       = (unsigned short*)(ws + 62914560);    //  2,097,152
  unsigned short* W4       = (unsigned short*)(ws + 65011712);    //  2,097,152
  unsigned short* gates    = (unsigned short*)(ws + 67108864);    // 41,943,040
  unsigned short* a_hidden = (unsigned short*)(ws + 109051904);   //  8,388,608
  float*          alpha    = (float*)(ws + 117440512);            //     16,384
  unsigned short* r1       = (unsigned short*)(ws + 117456896);   //  8,388,608
  unsigned short* r2       = (unsigned short*)(ws + 125845504);   //  8,388,608
  float*          residual = (float*)(ws + 134234112);            // 16,777,216

  float* h_out   = (float*)d_out;
  float* c_out   = h_out + (size_t)B_DIM * H_DIM;
  float* ssg_out = c_out + (size_t)B_DIM * H_DIM;

  prep_kernel<<<4096, 256, 0, stream>>>(x, h_prev, ssg_state, Wx, Ux, a1_w,
                                        ssg_w, r1_w, r2_w, r3_w,
                                        combined, ssg_in, hprev_bf, W1, W2, W3, W4);

  gemm8p_mode0<<<(B_DIM / 128) * (N1 / 256), 512, 0, stream>>>(
      combined, W1, bWx, bUx, a1_b, gates, a_hidden);

  gemm_bf16<1><<<(B_DIM / 128) * (N2 / 128), 256, 0, stream>>>(
      ssg_in, hprev_bf, W2, B_DIM, N2, 1024, ssg_b, r1_b, ssg_out, r1);

  gemm_bf16<2><<<(B_DIM / 128) * (1024 / 128), 256, 0, stream>>>(
      r1, r1, W3, B_DIM, 1024, 1024, r2_b, nullptr, r2, nullptr);

  gemm_bf16<3><<<(B_DIM / 128) * (1024 / 128), 256, 0, stream>>>(
      r2, r2, W4, B_DIM, 1024, 1024, r3_b, nullptr, residual, nullptr);

  alpha_kernel<<<B_DIM / 4, 256, 0, stream>>>(a_hidden, a2_w, a2_b, alpha);

  final_elem_kernel<<<(B_DIM * H_DIM / 4) / 256, 256, 0, stream>>>(
      gates, c_prev, alpha, residual, ssg_out, h_out, c_out);
}